// Round 6
// baseline (299.869 us; speedup 1.0000x reference)
//
#include <hip/hip_runtime.h>

#define TPB 256
#define RPT 4                    // rows per thread (2 interleaved pairs)
#define DD 5
#define F4PT 5                   // float4 per thread
#define F4PB (TPB * F4PT)        // 1280 float4 per block (20 KiB LDS)

#define INV2PI 0.15915494309189535f
#define LN2f   0.6931471805599453f
#define C2f    108.79849079439689f   /* 12*2pi/ln2 */

typedef float vf4 __attribute__((ext_vector_type(4)));   // nontemporal-store-compatible

// Constant block layout in d_ws (floats):
//  [0..24]  W1a = W1 * (1/2pi)     [25..49] W1b = W1 * (ln2/2pi)
//  [50..74] M   = (2W2)^2          [75..79] e = A*d + d
//  [80..84] b1c = b1/2pi           [85..89] b1t = b1*(12/ln2)
#define NCST 90

__device__ __forceinline__ void vpin(float& x) { asm volatile("" : "+v"(x)); }

__device__ __forceinline__ void compute_consts(const float* __restrict__ W1,
                                               const float* __restrict__ b1,
                                               const float* __restrict__ W2,
                                               const float* __restrict__ b2,
                                               float* cst)
{
#pragma unroll
    for (int i = 0; i < 25; ++i) {
        float w = W1[i];
        cst[i]      = w * INV2PI;
        cst[25 + i] = w * (LN2f * INV2PI);
    }
    float A[25], dv[DD];
#pragma unroll
    for (int j = 0; j < DD; ++j) {
        float s = 0.0f;
#pragma unroll
        for (int k = 0; k < DD; ++k) {
            float w = W2[j * DD + k];
            A[j * DD + k] = 2.0f * w;
            s += w;
        }
        dv[j] = b2[j] - 4.0f - 8.0f * s;
    }
#pragma unroll
    for (int j = 0; j < DD; ++j)
#pragma unroll
        for (int k = 0; k < DD; ++k) {
            float acc = 0.0f;
#pragma unroll
            for (int m = 0; m < DD; ++m) acc = fmaf(A[j * DD + m], A[m * DD + k], acc);
            cst[50 + j * DD + k] = acc;
        }
#pragma unroll
    for (int j = 0; j < DD; ++j) {
        float acc = dv[j];
#pragma unroll
        for (int m = 0; m < DD; ++m) acc = fmaf(A[j * DD + m], dv[m], acc);
        cst[75 + j] = acc;
    }
#pragma unroll
    for (int j = 0; j < DD; ++j) {
        cst[80 + j] = b1[j] * INV2PI;
        cst[85 + j] = b1[j] * (12.0f / LN2f);
    }
}

__global__ void prep_kernel(const float* __restrict__ W1, const float* __restrict__ b1,
                            const float* __restrict__ W2, const float* __restrict__ b2,
                            float* __restrict__ cst)
{
    if (threadIdx.x == 0 && blockIdx.x == 0) {
        float c[NCST];
        compute_consts(W1, b1, W2, b2, c);
        for (int i = 0; i < NCST; ++i) cst[i] = c[i];
    }
}

// Two independent rows, stage-interleaved for ILP. Weights in SGPRs (1 SGPR
// operand per FMA), biases pre-pinned in VGPRs (no v_mov per chain start).
__device__ __forceinline__ void process_pair(float* __restrict__ fa, float* __restrict__ fb,
                                             const float* w1a, const float* w1b,
                                             const float* m,
                                             const float* evv, const float* b1cv,
                                             const float* b1tv)
{
    float va[DD], vb[DD], ta[DD], tb[DD], ua[DD], ub[DD];
#pragma unroll
    for (int c = 0; c < DD; ++c) {
        va[c] = fmaf(fa[c], 8.0f * INV2PI, 7.0f * INV2PI);
        vb[c] = fmaf(fb[c], 8.0f * INV2PI, 7.0f * INV2PI);
    }
#pragma unroll
    for (int it = 0; it < 3; ++it) {
#pragma unroll
        for (int c = 0; c < DD; ++c) {
            ta[c] = __builtin_amdgcn_cosf(va[c]);
            tb[c] = __builtin_amdgcn_cosf(vb[c]);
        }
#pragma unroll
        for (int j = 0; j < DD; ++j) {
            float aa = fmaf(ta[0], w1a[j * DD + 0], b1cv[j]);
            float ab = fmaf(tb[0], w1a[j * DD + 0], b1cv[j]);
#pragma unroll
            for (int k = 1; k < DD; ++k) {
                aa = fmaf(ta[k], w1a[j * DD + k], aa);
                ab = fmaf(tb[k], w1a[j * DD + k], ab);
            }
            ua[j] = aa; ub[j] = ab;
        }
#pragma unroll
        for (int c = 0; c < DD; ++c) {
            ta[c] = __builtin_amdgcn_sinf(ua[c]);
            tb[c] = __builtin_amdgcn_sinf(ub[c]);
        }
#pragma unroll
        for (int j = 0; j < DD; ++j) {
            float aa = fmaf(ta[0], m[j * DD + 0], evv[j]);
            float ab = fmaf(tb[0], m[j * DD + 0], evv[j]);
#pragma unroll
            for (int k = 1; k < DD; ++k) {
                aa = fmaf(ta[k], m[j * DD + k], aa);
                ab = fmaf(tb[k], m[j * DD + k], ab);
            }
            ua[j] = aa; ub[j] = ab;
        }
#pragma unroll
        for (int c = 0; c < DD; ++c) {
            ta[c] = __builtin_amdgcn_logf(ua[c]);   // log2
            tb[c] = __builtin_amdgcn_logf(ub[c]);
        }
        if (it < 2) {
#pragma unroll
            for (int j = 0; j < DD; ++j) {
                float aa = fmaf(ta[0], w1b[j * DD + 0], b1cv[j]);
                float ab = fmaf(tb[0], w1b[j * DD + 0], b1cv[j]);
#pragma unroll
                for (int k = 1; k < DD; ++k) {
                    aa = fmaf(ta[k], w1b[j * DD + k], aa);
                    ab = fmaf(tb[k], w1b[j * DD + k], ab);
                }
                va[j] = aa; vb[j] = ab;
            }
        } else {
#pragma unroll
            for (int c = 0; c < DD; ++c) { ta[c] *= C2f; tb[c] *= C2f; }
#pragma unroll
            for (int j = 0; j < DD; ++j) {
                float aa = fmaf(ta[0], w1b[j * DD + 0], b1tv[j]);
                float ab = fmaf(tb[0], w1b[j * DD + 0], b1tv[j]);
#pragma unroll
                for (int k = 1; k < DD; ++k) {
                    aa = fmaf(ta[k], w1b[j * DD + k], aa);
                    ab = fmaf(tb[k], w1b[j * DD + k], ab);
                }
                va[j] = aa; vb[j] = ab;
            }
        }
    }
    // tanh(6x) = 1 - 2/(exp2(z)+1)
#pragma unroll
    for (int c = 0; c < DD; ++c) {
        float ea = __builtin_amdgcn_exp2f(va[c]);
        float eb = __builtin_amdgcn_exp2f(vb[c]);
        fa[c] = fmaf(__builtin_amdgcn_rcpf(ea + 1.0f), -2.0f, 1.0f);
        fb[c] = fmaf(__builtin_amdgcn_rcpf(eb + 1.0f), -2.0f, 1.0f);
    }
}

template <bool LOCAL_CST>
__device__ __forceinline__ void uber_body(const float* __restrict__ x,
                                          const float* __restrict__ cstg,
                                          const float* __restrict__ W1,
                                          const float* __restrict__ b1,
                                          const float* __restrict__ W2,
                                          const float* __restrict__ b2,
                                          float* __restrict__ out)
{
    __shared__ vf4 lds[F4PB];
    const int tid = threadIdx.x;
    const long long base4 = (long long)blockIdx.x * F4PB;

    const vf4* __restrict__ src4 = reinterpret_cast<const vf4*>(x) + base4;
    vf4* __restrict__ dst4 = reinterpret_cast<vf4*>(out) + base4;

    // ---- stage in (coalesced float4) ----
    vf4 stg[F4PT];
#pragma unroll
    for (int k = 0; k < F4PT; ++k) stg[k] = src4[k * TPB + tid];

    // ---- constants: weights -> SGPR; biases -> pinned VGPRs ----
    float lc[LOCAL_CST ? NCST : 1];
    const float* cst;
    if (LOCAL_CST) {
        compute_consts(W1, b1, W2, b2, lc);
        cst = lc;
    } else {
        cst = cstg;
    }
    float w1a[25], w1b[25], m[25];
#pragma unroll
    for (int i = 0; i < 25; ++i) { w1a[i] = cst[i]; w1b[i] = cst[25 + i]; m[i] = cst[50 + i]; }
    float evv[DD], b1cv[DD], b1tv[DD];
#pragma unroll
    for (int i = 0; i < DD; ++i) {
        evv[i] = cst[75 + i];  vpin(evv[i]);
        b1cv[i] = cst[80 + i]; vpin(b1cv[i]);
        b1tv[i] = cst[85 + i]; vpin(b1tv[i]);
    }

#pragma unroll
    for (int k = 0; k < F4PT; ++k) lds[k * TPB + tid] = stg[k];
    __syncthreads();

    float f[RPT * DD];
#pragma unroll
    for (int j = 0; j < F4PT; ++j) {
        vf4 t = lds[F4PT * tid + j];
        f[4 * j + 0] = t.x; f[4 * j + 1] = t.y;
        f[4 * j + 2] = t.z; f[4 * j + 3] = t.w;
    }

    process_pair(f,          f + DD,     w1a, w1b, m, evv, b1cv, b1tv);
    process_pair(f + 2 * DD, f + 3 * DD, w1a, w1b, m, evv, b1cv, b1tv);

#pragma unroll
    for (int j = 0; j < F4PT; ++j) {
        vf4 t;
        t.x = f[4 * j + 0]; t.y = f[4 * j + 1];
        t.z = f[4 * j + 2]; t.w = f[4 * j + 3];
        lds[F4PT * tid + j] = t;
    }
    __syncthreads();
#pragma unroll
    for (int k = 0; k < F4PT; ++k)
        __builtin_nontemporal_store(lds[k * TPB + tid], &dst4[k * TPB + tid]);
}

__global__ __launch_bounds__(TPB, 4)
void uber_main(const float* __restrict__ x, const float* __restrict__ cst,
               float* __restrict__ out)
{
    uber_body<false>(x, cst, nullptr, nullptr, nullptr, nullptr, out);
}

__global__ void uber_local(const float* __restrict__ x,
                           const float* __restrict__ W1, const float* __restrict__ b1,
                           const float* __restrict__ W2, const float* __restrict__ b2,
                           float* __restrict__ out)
{
    uber_body<true>(x, nullptr, W1, b1, W2, b2, out);
}

extern "C" void kernel_launch(void* const* d_in, const int* in_sizes, int n_in,
                              void* d_out, int out_size, void* d_ws, size_t ws_size,
                              hipStream_t stream) {
    const float* x  = (const float*)d_in[0];
    const float* W1 = (const float*)d_in[1];
    const float* b1 = (const float*)d_in[2];
    const float* W2 = (const float*)d_in[3];
    const float* b2 = (const float*)d_in[4];
    float* out = (float*)d_out;

    const int rows = in_sizes[0] / DD;         // 8388608
    const int grid = rows / (TPB * RPT);       // 8192 blocks, exact

    if (ws_size >= NCST * sizeof(float)) {
        float* cst = (float*)d_ws;
        prep_kernel<<<1, 64, 0, stream>>>(W1, b1, W2, b2, cst);
        uber_main<<<grid, TPB, 0, stream>>>(x, cst, out);
    } else {
        uber_local<<<grid, TPB, 0, stream>>>(x, W1, b1, W2, b2, out);
    }
}